// Round 8
// baseline (1952.076 us; speedup 1.0000x reference)
//
#include <hip/hip_runtime.h>
#include <math.h>
#include <stdint.h>

// Fused LSTM, v7: per-gate mixed-precision fp16 MFMA + 2 blocks/CU.
// gates i,f,o: 1-term (h_hi @ W_hi); gate g: 2-term ((h_hi+h_lo) @ W_hi),
// g's hi/lo as two PARALLEL 4-deep chains combined scalar at the end.
// EPB=2 -> 512 blocks -> 2 independent recurrences per CU: one block's MFMA
// phase overlaps the other's activation/barrier phase (latency hiding across
// blocks, since within a block the per-step critical path is serial).
// Real batch rows at tile rows {0,4}; lanes q>=2 are phantom (no writes).

constexpr int Bsz = 1024;
constexpr int Ssz = 1024;
constexpr int Hh  = 128;
constexpr int NT  = 512;
constexpr int EPB = 2;

using half8 = __attribute__((ext_vector_type(8))) _Float16;
using f32x4 = __attribute__((ext_vector_type(4))) float;

__device__ __forceinline__ float sigm2(float p) {      // 1/(1+2^-p)
    return __builtin_amdgcn_rcpf(1.0f + exp2f(-p));
}
__device__ __forceinline__ float tanh2(float p) {      // tanh with p=2x*log2e
    return 1.0f - 2.0f * __builtin_amdgcn_rcpf(1.0f + exp2f(p));
}

// byte offset of k within a 256 B fragment-contiguous A-row (K=128 fp16)
__device__ __forceinline__ int kbyte_of_u(int k) {
    return ((k >> 5) << 6) + (((k & 15) >> 2) << 4)
         + (((k & 3) + ((k >> 4) & 1) * 4) << 1);
}

__global__ __launch_bounds__(NT)
__attribute__((amdgpu_waves_per_eu(4)))
void lstm_mfma7(const float* __restrict__ x,  const float* __restrict__ Wi,
                const float* __restrict__ Wh, const float* __restrict__ bias,
                const float* __restrict__ Wd, const float* __restrict__ bd,
                float* __restrict__ out)
{
    __shared__ float xs[Ssz][EPB];                        // 8 KB x^T
    __shared__ __align__(16) uint16_t Ahi[2][16 * Hh];    // 2x4 KB h_hi fp16
    __shared__ __align__(16) uint16_t Alo[2][16 * Hh];    // 2x4 KB h_lo fp16
    __shared__ float red[2 * Hh];                         // 1 KB epilogue

    const int t  = threadIdx.x;
    const int w  = t >> 6;                 // wave 0..7
    const int l  = t & 63;
    const int q  = l >> 4;                 // C tile row 4q; real iff q<2
    const int cl = l & 15;
    const int b0 = blockIdx.x * EPB;
    const int u  = 16 * w + cl;            // this lane's hidden unit

    const float L2E = 1.4426950408889634f;

    // stage x transposed (coalesced, one-time)
    for (int i = t; i < EPB * Ssz; i += NT) {
        int e = i >> 10, s = i & (Ssz - 1);
        xs[s][e] = x[(size_t)(b0 + e) * Ssz + s];
    }
    // zero A buffers (rows != {0,4} stay zero forever)
    {
        uint32_t* pa = (uint32_t*)Ahi;
        uint32_t* pb = (uint32_t*)Alo;
        for (int i = t; i < 2048; i += NT) { pa[i] = 0u; pb[i] = 0u; }
    }

    // B fragments: W_hi fp16 pre-scaled by log2e (2*log2e for g-gate)
    half8 Bf[4][4];
    #pragma unroll
    for (int g = 0; g < 4; ++g) {
        const float sc = (g == 2) ? 2.0f * L2E : L2E;
        const int colabs = g * Hh + u;
        #pragma unroll
        for (int kt = 0; kt < 4; ++kt) {
            #pragma unroll
            for (int j = 0; j < 8; ++j) {
                int k = kt * 32 + ((j >> 2) << 4) + q * 4 + (j & 3);
                Bf[g][kt][j] = (_Float16)(Wh[k * 512 + colabs] * sc);
            }
        }
    }
    float wi_g[4], b_g[4];
    #pragma unroll
    for (int g = 0; g < 4; ++g) {
        const float sc = (g == 2) ? 2.0f * L2E : L2E;
        wi_g[g] = Wi[g * Hh + u] * sc;
        b_g[g]  = bias[g * Hh + u] * sc;
    }

    // A-frag read offsets (row cl; rotation keeps reads conflict-free)
    int roff[4];
    #pragma unroll
    for (int kt = 0; kt < 4; ++kt)
        roff[kt] = cl * 256 + ((kt * 64 + q * 16 + cl * 16) & 255);
    const bool aload = ((cl & 3) == 0) && (cl < 8);   // rows 0,4 only
    const bool wreal = (q < 2);
    const int woff = (q * 4) * 256 + ((kbyte_of_u(u) + q * 64) & 255);
    const int qx = q & 1;                  // phantom lanes borrow a real x

    half8 ah[4], al[4];
    #pragma unroll
    for (int kt = 0; kt < 4; ++kt) {
        ah[kt] = (half8)(_Float16)0.0f;
        al[kt] = (half8)(_Float16)0.0f;
    }
    const f32x4 zv = (f32x4){0.f, 0.f, 0.f, 0.f};

    float cst = 0.f, h_st = 0.f;
    __syncthreads();

    for (int s = 0; s < Ssz; ++s) {
        const char* Ah = (const char*)&Ahi[s & 1][0];
        const char* Al = (const char*)&Alo[s & 1][0];
        if (aload) {
            #pragma unroll
            for (int kt = 0; kt < 4; ++kt) {
                ah[kt] = *(const half8*)(Ah + roff[kt]);
                al[kt] = *(const half8*)(Al + roff[kt]);
            }
        }
        __builtin_amdgcn_s_setprio(1);
        // five parallel 4-deep chains: i, f, o, g_hi, g_lo
        f32x4 ci, cf, co, cg, cl2;
        ci  = __builtin_amdgcn_mfma_f32_16x16x32_f16(ah[0], Bf[0][0], zv, 0, 0, 0);
        cf  = __builtin_amdgcn_mfma_f32_16x16x32_f16(ah[0], Bf[1][0], zv, 0, 0, 0);
        co  = __builtin_amdgcn_mfma_f32_16x16x32_f16(ah[0], Bf[3][0], zv, 0, 0, 0);
        cg  = __builtin_amdgcn_mfma_f32_16x16x32_f16(ah[0], Bf[2][0], zv, 0, 0, 0);
        cl2 = __builtin_amdgcn_mfma_f32_16x16x32_f16(al[0], Bf[2][0], zv, 0, 0, 0);
        #pragma unroll
        for (int kt = 1; kt < 4; ++kt) {
            ci  = __builtin_amdgcn_mfma_f32_16x16x32_f16(ah[kt], Bf[0][kt], ci, 0, 0, 0);
            cf  = __builtin_amdgcn_mfma_f32_16x16x32_f16(ah[kt], Bf[1][kt], cf, 0, 0, 0);
            co  = __builtin_amdgcn_mfma_f32_16x16x32_f16(ah[kt], Bf[3][kt], co, 0, 0, 0);
            cg  = __builtin_amdgcn_mfma_f32_16x16x32_f16(ah[kt], Bf[2][kt], cg, 0, 0, 0);
            cl2 = __builtin_amdgcn_mfma_f32_16x16x32_f16(al[kt], Bf[2][kt], cl2, 0, 0, 0);
        }
        __builtin_amdgcn_s_setprio(0);

        const float xv = xs[s][qx];
        float ig = sigm2(ci[0] + fmaf(xv, wi_g[0], b_g[0]));
        float fg = sigm2(cf[0] + fmaf(xv, wi_g[1], b_g[1]));
        float og = sigm2(co[0] + fmaf(xv, wi_g[3], b_g[3]));
        float gg = tanh2((cg[0] + cl2[0]) + fmaf(xv, wi_g[2], b_g[2]));
        cst  = fmaf(fg, cst, ig * gg);
        h_st = og * tanh2(cst * (2.0f * L2E));
        _Float16 hh = (_Float16)h_st;
        _Float16 hl = (_Float16)(h_st - (float)hh);
        if (wreal) {
            *(uint16_t*)((char*)&Ahi[(s + 1) & 1][0] + woff) =
                __builtin_bit_cast(unsigned short, hh);
            *(uint16_t*)((char*)&Alo[(s + 1) & 1][0] + woff) =
                __builtin_bit_cast(unsigned short, hl);
        }
        __syncthreads();
    }

    // epilogue: out[b] = h_final @ Wd + bd
    if (wreal) red[q * Hh + u] = h_st * Wd[u];
    __syncthreads();
    if (t < EPB) {
        float acc = bd[0];
        for (int k = 0; k < Hh; ++k) acc += red[t * Hh + k];
        out[b0 + t] = acc;
    }
}

extern "C" void kernel_launch(void* const* d_in, const int* in_sizes, int n_in,
                              void* d_out, int out_size, void* d_ws, size_t ws_size,
                              hipStream_t stream) {
    const float* x    = (const float*)d_in[0];
    const float* Wi   = (const float*)d_in[1];
    const float* Wh   = (const float*)d_in[2];
    const float* bias = (const float*)d_in[3];
    const float* Wd   = (const float*)d_in[4];
    const float* bd   = (const float*)d_in[5];
    float* out = (float*)d_out;

    lstm_mfma7<<<dim3(Bsz / EPB), dim3(NT), 0, stream>>>(x, Wi, Wh, bias, Wd, bd, out);
}

// Round 9
// 1635.334 us; speedup vs baseline: 1.1937x; 1.1937x over previous
//
#include <hip/hip_runtime.h>
#include <math.h>
#include <stdint.h>

// Fused LSTM, v8: per-gate mixed-precision fp16 MFMA + 2 blocks/CU.
// gates i,f,o: 1-term (h_hi @ W_hi); gate g: 2-term ((h_hi+h_lo) @ W_hi)
// chained 8-deep on one accumulator (saves a register quad; cross-block
// overlap hides the chain latency).
// EPB=2 -> 512 blocks -> 2 independent recurrences per CU: one block's MFMA
// phase overlaps the other's activation/barrier phase.
// v8 fix vs v7: amdgpu_waves_per_eu(4,4) PINS 4 waves/EU -> VGPR cap 128
// (v7's min-only (4) let the compiler chase 8 waves/EU, cap 64 -> massive
// spills: VGPR=64, WRITE_SIZE=16 MB scratch).
// Real batch rows at tile rows {0,4}; lanes q>=2 are phantom (no writes).

constexpr int Bsz = 1024;
constexpr int Ssz = 1024;
constexpr int Hh  = 128;
constexpr int NT  = 512;
constexpr int EPB = 2;

using half8 = __attribute__((ext_vector_type(8))) _Float16;
using f32x4 = __attribute__((ext_vector_type(4))) float;

__device__ __forceinline__ float sigm2(float p) {      // 1/(1+2^-p)
    return __builtin_amdgcn_rcpf(1.0f + exp2f(-p));
}
__device__ __forceinline__ float tanh2(float p) {      // tanh with p=2x*log2e
    return 1.0f - 2.0f * __builtin_amdgcn_rcpf(1.0f + exp2f(p));
}

// byte offset of k within a 256 B fragment-contiguous A-row (K=128 fp16)
__device__ __forceinline__ int kbyte_of_u(int k) {
    return ((k >> 5) << 6) + (((k & 15) >> 2) << 4)
         + (((k & 3) + ((k >> 4) & 1) * 4) << 1);
}

__global__ __launch_bounds__(NT)
__attribute__((amdgpu_waves_per_eu(4, 4)))
void lstm_mfma8(const float* __restrict__ x,  const float* __restrict__ Wi,
                const float* __restrict__ Wh, const float* __restrict__ bias,
                const float* __restrict__ Wd, const float* __restrict__ bd,
                float* __restrict__ out)
{
    __shared__ float xs[Ssz][EPB];                        // 8 KB x^T
    __shared__ __align__(16) uint16_t Ahi[2][16 * Hh];    // 2x4 KB h_hi fp16
    __shared__ __align__(16) uint16_t Alo[2][16 * Hh];    // 2x4 KB h_lo fp16
    __shared__ float red[2 * Hh];                         // 1 KB epilogue

    const int t  = threadIdx.x;
    const int w  = t >> 6;                 // wave 0..7
    const int l  = t & 63;
    const int q  = l >> 4;                 // C tile row 4q; real iff q<2
    const int cl = l & 15;
    const int b0 = blockIdx.x * EPB;
    const int u  = 16 * w + cl;            // this lane's hidden unit

    const float L2E = 1.4426950408889634f;

    // stage x transposed (coalesced, one-time)
    for (int i = t; i < EPB * Ssz; i += NT) {
        int e = i >> 10, s = i & (Ssz - 1);
        xs[s][e] = x[(size_t)(b0 + e) * Ssz + s];
    }
    // zero A buffers (rows != {0,4} stay zero forever)
    {
        uint32_t* pa = (uint32_t*)Ahi;
        uint32_t* pb = (uint32_t*)Alo;
        for (int i = t; i < 2048; i += NT) { pa[i] = 0u; pb[i] = 0u; }
    }

    // B fragments: W_hi fp16 pre-scaled by log2e (2*log2e for g-gate)
    half8 Bf[4][4];
    #pragma unroll
    for (int g = 0; g < 4; ++g) {
        const float sc = (g == 2) ? 2.0f * L2E : L2E;
        const int colabs = g * Hh + u;
        #pragma unroll
        for (int kt = 0; kt < 4; ++kt) {
            #pragma unroll
            for (int j = 0; j < 8; ++j) {
                int k = kt * 32 + ((j >> 2) << 4) + q * 4 + (j & 3);
                Bf[g][kt][j] = (_Float16)(Wh[k * 512 + colabs] * sc);
            }
        }
    }
    float wi_g[4], b_g[4];
    #pragma unroll
    for (int g = 0; g < 4; ++g) {
        const float sc = (g == 2) ? 2.0f * L2E : L2E;
        wi_g[g] = Wi[g * Hh + u] * sc;
        b_g[g]  = bias[g * Hh + u] * sc;
    }

    // A-frag read offsets (row cl; rotation keeps reads conflict-free)
    int roff[4];
    #pragma unroll
    for (int kt = 0; kt < 4; ++kt)
        roff[kt] = cl * 256 + ((kt * 64 + q * 16 + cl * 16) & 255);
    const bool aload = ((cl & 3) == 0) && (cl < 8);   // rows 0,4 only
    const bool wreal = (q < 2);
    const int woff = (q * 4) * 256 + ((kbyte_of_u(u) + q * 64) & 255);
    const int qx = q & 1;                  // phantom lanes borrow a real x

    half8 ah[4], al[4];
    #pragma unroll
    for (int kt = 0; kt < 4; ++kt) {
        ah[kt] = (half8)(_Float16)0.0f;
        al[kt] = (half8)(_Float16)0.0f;
    }
    const f32x4 zv = (f32x4){0.f, 0.f, 0.f, 0.f};

    float cst = 0.f, h_st = 0.f;
    __syncthreads();

    for (int s = 0; s < Ssz; ++s) {
        const char* Ah = (const char*)&Ahi[s & 1][0];
        const char* Al = (const char*)&Alo[s & 1][0];
        if (aload) {
            #pragma unroll
            for (int kt = 0; kt < 4; ++kt) {
                ah[kt] = *(const half8*)(Ah + roff[kt]);
                al[kt] = *(const half8*)(Al + roff[kt]);
            }
        }
        __builtin_amdgcn_s_setprio(1);
        // chains: i, f, o 4-deep; g 8-deep (hi then lo on one accumulator)
        f32x4 ci, cf, co, cg;
        ci = __builtin_amdgcn_mfma_f32_16x16x32_f16(ah[0], Bf[0][0], zv, 0, 0, 0);
        cf = __builtin_amdgcn_mfma_f32_16x16x32_f16(ah[0], Bf[1][0], zv, 0, 0, 0);
        co = __builtin_amdgcn_mfma_f32_16x16x32_f16(ah[0], Bf[3][0], zv, 0, 0, 0);
        cg = __builtin_amdgcn_mfma_f32_16x16x32_f16(ah[0], Bf[2][0], zv, 0, 0, 0);
        #pragma unroll
        for (int kt = 1; kt < 4; ++kt) {
            ci = __builtin_amdgcn_mfma_f32_16x16x32_f16(ah[kt], Bf[0][kt], ci, 0, 0, 0);
            cf = __builtin_amdgcn_mfma_f32_16x16x32_f16(ah[kt], Bf[1][kt], cf, 0, 0, 0);
            co = __builtin_amdgcn_mfma_f32_16x16x32_f16(ah[kt], Bf[3][kt], co, 0, 0, 0);
            cg = __builtin_amdgcn_mfma_f32_16x16x32_f16(ah[kt], Bf[2][kt], cg, 0, 0, 0);
        }
        #pragma unroll
        for (int kt = 0; kt < 4; ++kt)
            cg = __builtin_amdgcn_mfma_f32_16x16x32_f16(al[kt], Bf[2][kt], cg, 0, 0, 0);
        __builtin_amdgcn_s_setprio(0);

        const float xv = xs[s][qx];
        float ig = sigm2(ci[0] + fmaf(xv, wi_g[0], b_g[0]));
        float fg = sigm2(cf[0] + fmaf(xv, wi_g[1], b_g[1]));
        float og = sigm2(co[0] + fmaf(xv, wi_g[3], b_g[3]));
        float gg = tanh2(cg[0] + fmaf(xv, wi_g[2], b_g[2]));
        cst  = fmaf(fg, cst, ig * gg);
        h_st = og * tanh2(cst * (2.0f * L2E));
        _Float16 hh = (_Float16)h_st;
        _Float16 hl = (_Float16)(h_st - (float)hh);
        if (wreal) {
            *(uint16_t*)((char*)&Ahi[(s + 1) & 1][0] + woff) =
                __builtin_bit_cast(unsigned short, hh);
            *(uint16_t*)((char*)&Alo[(s + 1) & 1][0] + woff) =
                __builtin_bit_cast(unsigned short, hl);
        }
        __syncthreads();
    }

    // epilogue: out[b] = h_final @ Wd + bd
    if (wreal) red[q * Hh + u] = h_st * Wd[u];
    __syncthreads();
    if (t < EPB) {
        float acc = bd[0];
        for (int k = 0; k < Hh; ++k) acc += red[t * Hh + k];
        out[b0 + t] = acc;
    }
}

extern "C" void kernel_launch(void* const* d_in, const int* in_sizes, int n_in,
                              void* d_out, int out_size, void* d_ws, size_t ws_size,
                              hipStream_t stream) {
    const float* x    = (const float*)d_in[0];
    const float* Wi   = (const float*)d_in[1];
    const float* Wh   = (const float*)d_in[2];
    const float* bias = (const float*)d_in[3];
    const float* Wd   = (const float*)d_in[4];
    const float* bd   = (const float*)d_in[5];
    float* out = (float*)d_out;

    lstm_mfma8<<<dim3(Bsz / EPB), dim3(NT), 0, stream>>>(x, Wi, Wh, bias, Wd, bd, out);
}

// Round 10
// 1084.116 us; speedup vs baseline: 1.8006x; 1.5084x over previous
//
#include <hip/hip_runtime.h>
#include <math.h>
#include <stdint.h>

// Fused LSTM, v9: per-gate mixed-precision fp16 MFMA + 2 blocks/CU.
// gates i,f,o: 1-term (h_hi @ W_hi); gate g: 2-term ((h_hi+h_lo) @ W_hi).
// EPB=2 -> 512 blocks -> 2 independent recurrences per CU: one block's MFMA
// phase overlaps the other's activation/barrier phase.
// v9 registers: __launch_bounds__(512,4) (documented: 4 waves/EU -> VGPR cap
// 128, 2 blocks/CU). Single ah[4] reused for lo-term loads (in-place reload
// after hi MFMAs issue; sched_barrier pins order) -> live set ~116 <= 128.
// (v7/v8 failed here: amdgpu_waves_per_eu gave cap 64 -> 12-16 MB spills.)
// Real batch rows at tile rows {0,4}; phantom lanes write rows {8,12} which
// are never read (aload pulls only rows 0,4; other A-rows stay zero).

constexpr int Bsz = 1024;
constexpr int Ssz = 1024;
constexpr int Hh  = 128;
constexpr int NT  = 512;
constexpr int EPB = 2;

using half8 = __attribute__((ext_vector_type(8))) _Float16;
using f32x4 = __attribute__((ext_vector_type(4))) float;

__device__ __forceinline__ float sigm2(float p) {      // 1/(1+2^-p)
    return __builtin_amdgcn_rcpf(1.0f + exp2f(-p));
}
__device__ __forceinline__ float tanh2(float p) {      // tanh with p=2x*log2e
    return 1.0f - 2.0f * __builtin_amdgcn_rcpf(1.0f + exp2f(p));
}

// byte offset of k within a 256 B fragment-contiguous A-row (K=128 fp16)
__device__ __forceinline__ int kbyte_of_u(int k) {
    return ((k >> 5) << 6) + (((k & 15) >> 2) << 4)
         + (((k & 3) + ((k >> 4) & 1) * 4) << 1);
}

__global__ __launch_bounds__(NT, 4)
void lstm_mfma9(const float* __restrict__ x,  const float* __restrict__ Wi,
                const float* __restrict__ Wh, const float* __restrict__ bias,
                const float* __restrict__ Wd, const float* __restrict__ bd,
                float* __restrict__ out)
{
    __shared__ float xs[Ssz][EPB];                        // 8 KB x^T
    __shared__ __align__(16) uint16_t Ahi[2][16 * Hh];    // 2x4 KB h_hi fp16
    __shared__ __align__(16) uint16_t Alo[2][16 * Hh];    // 2x4 KB h_lo fp16
    __shared__ float red[2 * Hh];                         // 1 KB epilogue

    const int t  = threadIdx.x;
    const int w  = t >> 6;                 // wave 0..7
    const int l  = t & 63;
    const int q  = l >> 4;                 // C tile row 4q; real iff q<2
    const int cl = l & 15;
    const int b0 = blockIdx.x * EPB;
    const int u  = 16 * w + cl;            // this lane's hidden unit

    const float L2E = 1.4426950408889634f;

    // stage x transposed (coalesced, one-time)
    for (int i = t; i < EPB * Ssz; i += NT) {
        int e = i >> 10, s = i & (Ssz - 1);
        xs[s][e] = x[(size_t)(b0 + e) * Ssz + s];
    }
    // zero A buffers (rows 1,2,3,5,6,7,... stay zero forever)
    {
        uint32_t* pa = (uint32_t*)Ahi;
        uint32_t* pb = (uint32_t*)Alo;
        for (int i = t; i < 2048; i += NT) { pa[i] = 0u; pb[i] = 0u; }
    }

    // B fragments: W_hi fp16 pre-scaled by log2e (2*log2e for g-gate)
    half8 Bf[4][4];
    #pragma unroll
    for (int g = 0; g < 4; ++g) {
        const float sc = (g == 2) ? 2.0f * L2E : L2E;
        const int colabs = g * Hh + u;
        #pragma unroll
        for (int kt = 0; kt < 4; ++kt) {
            #pragma unroll
            for (int j = 0; j < 8; ++j) {
                int k = kt * 32 + ((j >> 2) << 4) + q * 4 + (j & 3);
                Bf[g][kt][j] = (_Float16)(Wh[k * 512 + colabs] * sc);
            }
        }
    }
    float wi_g[4], b_g[4];
    #pragma unroll
    for (int g = 0; g < 4; ++g) {
        const float sc = (g == 2) ? 2.0f * L2E : L2E;
        wi_g[g] = Wi[g * Hh + u] * sc;
        b_g[g]  = bias[g * Hh + u] * sc;
    }

    // A-frag read offsets (row cl; rotation keeps reads conflict-free)
    int roff[4];
    #pragma unroll
    for (int kt = 0; kt < 4; ++kt)
        roff[kt] = cl * 256 + ((kt * 64 + q * 16 + cl * 16) & 255);
    const bool aload = ((cl & 3) == 0) && (cl < 8);   // rows 0,4 only
    // all lanes write; q>=2 lands in rows 8,12 (never read)
    const int woff = (q * 4) * 256 + ((kbyte_of_u(u) + q * 64) & 255);
    const int qx = q & 1;                  // phantom lanes borrow a real x

    half8 ah[4];
    #pragma unroll
    for (int kt = 0; kt < 4; ++kt) ah[kt] = (half8)(_Float16)0.0f;
    const f32x4 zv = (f32x4){0.f, 0.f, 0.f, 0.f};

    float cst = 0.f, h_st = 0.f;
    __syncthreads();

    for (int s = 0; s < Ssz; ++s) {
        const char* Ah = (const char*)&Ahi[s & 1][0];
        const char* Al = (const char*)&Alo[s & 1][0];
        if (aload) {
            #pragma unroll
            for (int kt = 0; kt < 4; ++kt)
                ah[kt] = *(const half8*)(Ah + roff[kt]);
        }
        __builtin_amdgcn_s_setprio(1);
        // chains: i, f, o, g_hi - four parallel 4-deep chains
        f32x4 ci, cf, co, cg;
        ci = __builtin_amdgcn_mfma_f32_16x16x32_f16(ah[0], Bf[0][0], zv, 0, 0, 0);
        cf = __builtin_amdgcn_mfma_f32_16x16x32_f16(ah[0], Bf[1][0], zv, 0, 0, 0);
        co = __builtin_amdgcn_mfma_f32_16x16x32_f16(ah[0], Bf[3][0], zv, 0, 0, 0);
        cg = __builtin_amdgcn_mfma_f32_16x16x32_f16(ah[0], Bf[2][0], zv, 0, 0, 0);
        #pragma unroll
        for (int kt = 1; kt < 4; ++kt) {
            ci = __builtin_amdgcn_mfma_f32_16x16x32_f16(ah[kt], Bf[0][kt], ci, 0, 0, 0);
            cf = __builtin_amdgcn_mfma_f32_16x16x32_f16(ah[kt], Bf[1][kt], cf, 0, 0, 0);
            co = __builtin_amdgcn_mfma_f32_16x16x32_f16(ah[kt], Bf[3][kt], co, 0, 0, 0);
            cg = __builtin_amdgcn_mfma_f32_16x16x32_f16(ah[kt], Bf[2][kt], cg, 0, 0, 0);
        }
        __builtin_amdgcn_s_setprio(0);
        // reload ah IN PLACE with lo values (WAR: after hi MFMAs consumed it)
        __builtin_amdgcn_sched_barrier(0);
        if (aload) {
            #pragma unroll
            for (int kt = 0; kt < 4; ++kt)
                ah[kt] = *(const half8*)(Al + roff[kt]);
        }
        __builtin_amdgcn_s_setprio(1);
        #pragma unroll
        for (int kt = 0; kt < 4; ++kt)
            cg = __builtin_amdgcn_mfma_f32_16x16x32_f16(ah[kt], Bf[2][kt], cg, 0, 0, 0);
        __builtin_amdgcn_s_setprio(0);

        const float xv = xs[s][qx];
        float ig = sigm2(ci[0] + fmaf(xv, wi_g[0], b_g[0]));
        float fg = sigm2(cf[0] + fmaf(xv, wi_g[1], b_g[1]));
        float og = sigm2(co[0] + fmaf(xv, wi_g[3], b_g[3]));
        float gg = tanh2(cg[0] + fmaf(xv, wi_g[2], b_g[2]));
        cst  = fmaf(fg, cst, ig * gg);
        h_st = og * tanh2(cst * (2.0f * L2E));
        _Float16 hh = (_Float16)h_st;
        _Float16 hl = (_Float16)(h_st - (float)hh);
        *(uint16_t*)((char*)&Ahi[(s + 1) & 1][0] + woff) =
            __builtin_bit_cast(unsigned short, hh);
        *(uint16_t*)((char*)&Alo[(s + 1) & 1][0] + woff) =
            __builtin_bit_cast(unsigned short, hl);
        __syncthreads();
    }

    // epilogue: out[b] = h_final @ Wd + bd
    if (q < 2) red[q * Hh + u] = h_st * Wd[u];
    __syncthreads();
    if (t < EPB) {
        float acc = bd[0];
        for (int k = 0; k < Hh; ++k) acc += red[t * Hh + k];
        out[b0 + t] = acc;
    }
}

extern "C" void kernel_launch(void* const* d_in, const int* in_sizes, int n_in,
                              void* d_out, int out_size, void* d_ws, size_t ws_size,
                              hipStream_t stream) {
    const float* x    = (const float*)d_in[0];
    const float* Wi   = (const float*)d_in[1];
    const float* Wh   = (const float*)d_in[2];
    const float* bias = (const float*)d_in[3];
    const float* Wd   = (const float*)d_in[4];
    const float* bd   = (const float*)d_in[5];
    float* out = (float*)d_out;

    lstm_mfma9<<<dim3(Bsz / EPB), dim3(NT), 0, stream>>>(x, Wi, Wh, bias, Wd, bd, out);
}

// Round 11
// 772.029 us; speedup vs baseline: 2.5285x; 1.4042x over previous
//
#include <hip/hip_runtime.h>
#include <math.h>
#include <stdint.h>

// Fused LSTM, v10: v6 structure + 2-deep MFMA chains.
// gates i,f,o: 1-term (h_hi @ W_hi); gate g: 2-term ((h_hi+h_lo) @ W_hi).
// 256 blocks x 512 threads (8 waves, 1 block/CU; Wh register-resident across
// the 8 waves -> any block subdivision doubles per-CU MFMA work: v9 lesson).
// v10 change: TEN 2-deep MFMA chains (each gate's 4 k-tiles split into two
// 2-deep chains, combined scalar) -> longest dependent-MFMA path 8 -> 2.
// (r6->r7 showed chain depth dominates the serial path: 8->4 deep saved
// ~330 cyc/step.) xg FMAs hoisted above the MFMA block.
// Real batch rows at tile rows {0,4,8,12}: acc[*][0] = own (elem q, unit u).

constexpr int Bsz = 1024;
constexpr int Ssz = 1024;
constexpr int Hh  = 128;
constexpr int NT  = 512;
constexpr int EPB = 4;

using half8 = __attribute__((ext_vector_type(8))) _Float16;
using f32x4 = __attribute__((ext_vector_type(4))) float;

__device__ __forceinline__ float sigm2(float p) {      // 1/(1+2^-p)
    return __builtin_amdgcn_rcpf(1.0f + exp2f(-p));
}
__device__ __forceinline__ float tanh2(float p) {      // tanh with p=2x*log2e
    return 1.0f - 2.0f * __builtin_amdgcn_rcpf(1.0f + exp2f(p));
}

// byte offset of k within a 256 B fragment-contiguous A-row (K=128 fp16)
__device__ __forceinline__ int kbyte_of_u(int k) {
    return ((k >> 5) << 6) + (((k & 15) >> 2) << 4)
         + (((k & 3) + ((k >> 4) & 1) * 4) << 1);
}

#define MFMA16(a, b, c) __builtin_amdgcn_mfma_f32_16x16x32_f16((a), (b), (c), 0, 0, 0)

__global__ __launch_bounds__(NT)
__attribute__((amdgpu_waves_per_eu(2, 2)))
void lstm_mfma10(const float* __restrict__ x,  const float* __restrict__ Wi,
                 const float* __restrict__ Wh, const float* __restrict__ bias,
                 const float* __restrict__ Wd, const float* __restrict__ bd,
                 float* __restrict__ out)
{
    __shared__ float xs[Ssz][EPB];                        // 16 KB x^T
    __shared__ __align__(16) uint16_t Ahi[2][16 * Hh];    // 2x4 KB h_hi fp16
    __shared__ __align__(16) uint16_t Alo[2][16 * Hh];    // 2x4 KB h_lo fp16
    __shared__ float red[NT];                             // 2 KB epilogue

    const int t  = threadIdx.x;
    const int w  = t >> 6;                 // wave 0..7
    const int l  = t & 63;
    const int q  = l >> 4;                 // elem (C tile row 4q)
    const int cl = l & 15;
    const int b0 = blockIdx.x * EPB;
    const int u  = 16 * w + cl;            // this lane's hidden unit

    const float L2E = 1.4426950408889634f;

    // stage x transposed (coalesced, one-time)
    for (int i = t; i < EPB * Ssz; i += NT) {
        int e = i >> 10, s = i & (Ssz - 1);
        xs[s][e] = x[(size_t)(b0 + e) * Ssz + s];
    }
    // zero A buffers (rows != {0,4,8,12} stay zero forever)
    {
        uint32_t* pa = (uint32_t*)Ahi;
        uint32_t* pb = (uint32_t*)Alo;
        for (int i = t; i < 2048; i += NT) { pa[i] = 0u; pb[i] = 0u; }
    }

    // B fragments: W_hi fp16 pre-scaled by log2e (2*log2e for g-gate)
    half8 Bf[4][4];
    #pragma unroll
    for (int g = 0; g < 4; ++g) {
        const float sc = (g == 2) ? 2.0f * L2E : L2E;
        const int colabs = g * Hh + u;
        #pragma unroll
        for (int kt = 0; kt < 4; ++kt) {
            #pragma unroll
            for (int j = 0; j < 8; ++j) {
                int k = kt * 32 + ((j >> 2) << 4) + q * 4 + (j & 3);
                Bf[g][kt][j] = (_Float16)(Wh[k * 512 + colabs] * sc);
            }
        }
    }
    float wi_g[4], b_g[4];
    #pragma unroll
    for (int g = 0; g < 4; ++g) {
        const float sc = (g == 2) ? 2.0f * L2E : L2E;
        wi_g[g] = Wi[g * Hh + u] * sc;
        b_g[g]  = bias[g * Hh + u] * sc;
    }

    // A-frag read offsets (row cl; rotation keeps reads conflict-free)
    int roff[4];
    #pragma unroll
    for (int kt = 0; kt < 4; ++kt)
        roff[kt] = cl * 256 + ((kt * 64 + q * 16 + cl * 16) & 255);
    const bool aload = ((cl & 3) == 0);
    const int woff = (q * 4) * 256 + ((kbyte_of_u(u) + q * 64) & 255);

    half8 ah[4], al[4];
    #pragma unroll
    for (int kt = 0; kt < 4; ++kt) {
        ah[kt] = (half8)(_Float16)0.0f;
        al[kt] = (half8)(_Float16)0.0f;
    }
    const f32x4 zv = (f32x4){0.f, 0.f, 0.f, 0.f};

    float cst = 0.f, h_st = 0.f;
    __syncthreads();

    for (int s = 0; s < Ssz; ++s) {
        const char* Ah = (const char*)&Ahi[s & 1][0];
        const char* Al = (const char*)&Alo[s & 1][0];
        // xg first: independent of the LDS reads, fills the read-latency gap
        const float xv = xs[s][q];
        const float xg0 = fmaf(xv, wi_g[0], b_g[0]);
        const float xg1 = fmaf(xv, wi_g[1], b_g[1]);
        const float xg2 = fmaf(xv, wi_g[2], b_g[2]);
        const float xg3 = fmaf(xv, wi_g[3], b_g[3]);
        if (aload) {
            #pragma unroll
            for (int kt = 0; kt < 4; ++kt) {
                ah[kt] = *(const half8*)(Ah + roff[kt]);
                al[kt] = *(const half8*)(Al + roff[kt]);
            }
        }
        __builtin_amdgcn_s_setprio(1);
        // ten 2-deep chains: i0,f0,o0,g0,gl0 (kt 0-1), i1,f1,o1,g1,gl1 (kt 2-3)
        f32x4 ci0 = MFMA16(ah[0], Bf[0][0], zv);
        f32x4 cf0 = MFMA16(ah[0], Bf[1][0], zv);
        f32x4 co0 = MFMA16(ah[0], Bf[3][0], zv);
        f32x4 cg0 = MFMA16(ah[0], Bf[2][0], zv);
        f32x4 gl0 = MFMA16(al[0], Bf[2][0], zv);
        f32x4 ci1 = MFMA16(ah[2], Bf[0][2], zv);
        f32x4 cf1 = MFMA16(ah[2], Bf[1][2], zv);
        f32x4 co1 = MFMA16(ah[2], Bf[3][2], zv);
        f32x4 cg1 = MFMA16(ah[2], Bf[2][2], zv);
        f32x4 gl1 = MFMA16(al[2], Bf[2][2], zv);
        ci0 = MFMA16(ah[1], Bf[0][1], ci0);
        cf0 = MFMA16(ah[1], Bf[1][1], cf0);
        co0 = MFMA16(ah[1], Bf[3][1], co0);
        cg0 = MFMA16(ah[1], Bf[2][1], cg0);
        gl0 = MFMA16(al[1], Bf[2][1], gl0);
        ci1 = MFMA16(ah[3], Bf[0][3], ci1);
        cf1 = MFMA16(ah[3], Bf[1][3], cf1);
        co1 = MFMA16(ah[3], Bf[3][3], co1);
        cg1 = MFMA16(ah[3], Bf[2][3], cg1);
        gl1 = MFMA16(al[3], Bf[2][3], gl1);
        __builtin_amdgcn_s_setprio(0);

        float ig = sigm2((ci0[0] + ci1[0]) + xg0);
        float fg = sigm2((cf0[0] + cf1[0]) + xg1);
        float og = sigm2((co0[0] + co1[0]) + xg3);
        float gg = tanh2(((cg0[0] + cg1[0]) + (gl0[0] + gl1[0])) + xg2);
        cst  = fmaf(fg, cst, ig * gg);
        h_st = og * tanh2(cst * (2.0f * L2E));
        _Float16 hh = (_Float16)h_st;
        _Float16 hl = (_Float16)(h_st - (float)hh);
        *(uint16_t*)((char*)&Ahi[(s + 1) & 1][0] + woff) =
            __builtin_bit_cast(unsigned short, hh);
        *(uint16_t*)((char*)&Alo[(s + 1) & 1][0] + woff) =
            __builtin_bit_cast(unsigned short, hl);
        __syncthreads();
    }

    // epilogue: out[b] = h_final @ Wd + bd (h_final in registers)
    red[q * Hh + u] = h_st * Wd[u];
    __syncthreads();
    if (t < EPB) {
        float acc = bd[0];
        for (int k = 0; k < Hh; ++k) acc += red[t * Hh + k];
        out[b0 + t] = acc;
    }
}

extern "C" void kernel_launch(void* const* d_in, const int* in_sizes, int n_in,
                              void* d_out, int out_size, void* d_ws, size_t ws_size,
                              hipStream_t stream) {
    const float* x    = (const float*)d_in[0];
    const float* Wi   = (const float*)d_in[1];
    const float* Wh   = (const float*)d_in[2];
    const float* bias = (const float*)d_in[3];
    const float* Wd   = (const float*)d_in[4];
    const float* bd   = (const float*)d_in[5];
    float* out = (float*)d_out;

    lstm_mfma10<<<dim3(Bsz / EPB), dim3(NT), 0, stream>>>(x, Wi, Wh, bias, Wd, bd, out);
}

// Round 12
// 599.390 us; speedup vs baseline: 3.2568x; 1.2880x over previous
//
#include <hip/hip_runtime.h>
#include <math.h>
#include <stdint.h>

// Fused LSTM, v11: single-term fp16 MFMA for ALL gates.
// gates = h_fp16 @ W_fp16 (h re-derived each step from fp32 c in registers,
// so quantization error does not compound in the state; v5 vs v6 showed
// absmax is dominated by W quantization, not dropped lo-terms).
// 16 MFMA/wave/step as four parallel 4-deep chains (i,f,g,o).
// 256 blocks x 512 threads (8 waves, 1 block/CU; Wh register-resident).
// Single fp16 h buffer (double-buffered), 4 ds_read_b128/lane/step,
// 1 ds_write_b16 + 1 barrier per step. exp2-folded weights; setprio on MFMA.
// Real batch rows at tile rows {0,4,8,12}: acc[g][0] = own (elem q, unit u).

constexpr int Bsz = 1024;
constexpr int Ssz = 1024;
constexpr int Hh  = 128;
constexpr int NT  = 512;
constexpr int EPB = 4;

using half8 = __attribute__((ext_vector_type(8))) _Float16;
using f32x4 = __attribute__((ext_vector_type(4))) float;

__device__ __forceinline__ float sigm2(float p) {      // 1/(1+2^-p)
    return __builtin_amdgcn_rcpf(1.0f + exp2f(-p));
}
__device__ __forceinline__ float tanh2(float p) {      // tanh with p=2x*log2e
    return 1.0f - 2.0f * __builtin_amdgcn_rcpf(1.0f + exp2f(p));
}

// byte offset of k within a 256 B fragment-contiguous A-row (K=128 fp16)
__device__ __forceinline__ int kbyte_of_u(int k) {
    return ((k >> 5) << 6) + (((k & 15) >> 2) << 4)
         + (((k & 3) + ((k >> 4) & 1) * 4) << 1);
}

#define MFMA16(a, b, c) __builtin_amdgcn_mfma_f32_16x16x32_f16((a), (b), (c), 0, 0, 0)

__global__ __launch_bounds__(NT)
__attribute__((amdgpu_waves_per_eu(2, 2)))
void lstm_mfma11(const float* __restrict__ x,  const float* __restrict__ Wi,
                 const float* __restrict__ Wh, const float* __restrict__ bias,
                 const float* __restrict__ Wd, const float* __restrict__ bd,
                 float* __restrict__ out)
{
    __shared__ float xs[Ssz][EPB];                        // 16 KB x^T
    __shared__ __align__(16) uint16_t Ahi[2][16 * Hh];    // 2x4 KB h fp16
    __shared__ float red[NT];                             // 2 KB epilogue

    const int t  = threadIdx.x;
    const int w  = t >> 6;                 // wave 0..7
    const int l  = t & 63;
    const int q  = l >> 4;                 // elem (C tile row 4q)
    const int cl = l & 15;
    const int b0 = blockIdx.x * EPB;
    const int u  = 16 * w + cl;            // this lane's hidden unit

    const float L2E = 1.4426950408889634f;

    // stage x transposed (coalesced, one-time)
    for (int i = t; i < EPB * Ssz; i += NT) {
        int e = i >> 10, s = i & (Ssz - 1);
        xs[s][e] = x[(size_t)(b0 + e) * Ssz + s];
    }
    // zero A buffers (rows != {0,4,8,12} stay zero forever)
    {
        uint32_t* pa = (uint32_t*)Ahi;
        for (int i = t; i < 2048; i += NT) pa[i] = 0u;
    }

    // B fragments: W fp16 pre-scaled by log2e (2*log2e for g-gate)
    half8 Bf[4][4];
    #pragma unroll
    for (int g = 0; g < 4; ++g) {
        const float sc = (g == 2) ? 2.0f * L2E : L2E;
        const int colabs = g * Hh + u;
        #pragma unroll
        for (int kt = 0; kt < 4; ++kt) {
            #pragma unroll
            for (int j = 0; j < 8; ++j) {
                int k = kt * 32 + ((j >> 2) << 4) + q * 4 + (j & 3);
                Bf[g][kt][j] = (_Float16)(Wh[k * 512 + colabs] * sc);
            }
        }
    }
    float wi_g[4], b_g[4];
    #pragma unroll
    for (int g = 0; g < 4; ++g) {
        const float sc = (g == 2) ? 2.0f * L2E : L2E;
        wi_g[g] = Wi[g * Hh + u] * sc;
        b_g[g]  = bias[g * Hh + u] * sc;
    }

    // A-frag read offsets (row cl; rotation keeps reads conflict-free)
    int roff[4];
    #pragma unroll
    for (int kt = 0; kt < 4; ++kt)
        roff[kt] = cl * 256 + ((kt * 64 + q * 16 + cl * 16) & 255);
    const bool aload = ((cl & 3) == 0);
    const int woff = (q * 4) * 256 + ((kbyte_of_u(u) + q * 64) & 255);

    half8 ah[4];
    #pragma unroll
    for (int kt = 0; kt < 4; ++kt) ah[kt] = (half8)(_Float16)0.0f;
    const f32x4 zv = (f32x4){0.f, 0.f, 0.f, 0.f};

    float cst = 0.f, h_st = 0.f;
    __syncthreads();

    for (int s = 0; s < Ssz; ++s) {
        const char* Ah = (const char*)&Ahi[s & 1][0];
        // xg first: independent of the LDS reads, fills the read-latency gap
        const float xv = xs[s][q];
        const float xg0 = fmaf(xv, wi_g[0], b_g[0]);
        const float xg1 = fmaf(xv, wi_g[1], b_g[1]);
        const float xg2 = fmaf(xv, wi_g[2], b_g[2]);
        const float xg3 = fmaf(xv, wi_g[3], b_g[3]);
        if (aload) {
            #pragma unroll
            for (int kt = 0; kt < 4; ++kt)
                ah[kt] = *(const half8*)(Ah + roff[kt]);
        }
        __builtin_amdgcn_s_setprio(1);
        // four parallel 4-deep chains: i, f, o, g
        f32x4 ci = MFMA16(ah[0], Bf[0][0], zv);
        f32x4 cf = MFMA16(ah[0], Bf[1][0], zv);
        f32x4 co = MFMA16(ah[0], Bf[3][0], zv);
        f32x4 cg = MFMA16(ah[0], Bf[2][0], zv);
        #pragma unroll
        for (int kt = 1; kt < 4; ++kt) {
            ci = MFMA16(ah[kt], Bf[0][kt], ci);
            cf = MFMA16(ah[kt], Bf[1][kt], cf);
            co = MFMA16(ah[kt], Bf[3][kt], co);
            cg = MFMA16(ah[kt], Bf[2][kt], cg);
        }
        __builtin_amdgcn_s_setprio(0);

        float ig = sigm2(ci[0] + xg0);
        float fg = sigm2(cf[0] + xg1);
        float og = sigm2(co[0] + xg3);
        float gg = tanh2(cg[0] + xg2);
        cst  = fmaf(fg, cst, ig * gg);
        h_st = og * tanh2(cst * (2.0f * L2E));
        *(uint16_t*)((char*)&Ahi[(s + 1) & 1][0] + woff) =
            __builtin_bit_cast(unsigned short, (_Float16)h_st);
        __syncthreads();
    }

    // epilogue: out[b] = h_final @ Wd + bd (h_final in registers)
    red[q * Hh + u] = h_st * Wd[u];
    __syncthreads();
    if (t < EPB) {
        float acc = bd[0];
        for (int k = 0; k < Hh; ++k) acc += red[t * Hh + k];
        out[b0 + t] = acc;
    }
}

extern "C" void kernel_launch(void* const* d_in, const int* in_sizes, int n_in,
                              void* d_out, int out_size, void* d_ws, size_t ws_size,
                              hipStream_t stream) {
    const float* x    = (const float*)d_in[0];
    const float* Wi   = (const float*)d_in[1];
    const float* Wh   = (const float*)d_in[2];
    const float* bias = (const float*)d_in[3];
    const float* Wd   = (const float*)d_in[4];
    const float* bd   = (const float*)d_in[5];
    float* out = (float*)d_out;

    lstm_mfma11<<<dim3(Bsz / EPB), dim3(NT), 0, stream>>>(x, Wi, Wh, bias, Wd, bd, out);
}